// Round 3
// baseline (967.708 us; speedup 1.0000x reference)
//
#include <hip/hip_runtime.h>
#include <math.h>

// WaveletDenoiser — R5: 2-blocks/CU fused pipeline.
//
// R4 post-mortem: latency-bound; conflicts (1.4e7) are median-histogram
// same-bin LDS atomics (pass-1 bins = float exponent byte, ~6 hot bins),
// NOT the dwt reads; 1 block/CU (127KB LDS) leaves barrier/tail bubbles
// unfilled.
// R5: (a) LDS 127->76.5KB (d1,d2 in regs, spilled into dead slots; rec1
//         fused into final idwt, +8% FMA) -> 2 blocks/CU, NT=512,
//         __launch_bounds__(512,4) caps VGPR at 128;
//     (b) wave-aggregated histogram atomics (ballot/leader);
//     (c) scan+select fused in wave 0 -> 12 barriers (was 19), median
//         histograms read registers.
// Per-output FMA order unchanged -> bit-identical to R4.

constexpr float HF[16] = {
  0.05441584224308161f,     0.3128715909144659f,     0.6756307362980128f,
  0.5853546836548691f,     -0.015829105256023893f,  -0.2840155429624281f,
  0.00047248457399797254f,  0.128747426620186f,     -0.01736930100202211f,
 -0.04408825393106472f,     0.013981027917015516f,   0.008746094047015655f,
 -0.00487035299301066f,    -0.0003917403729959771f,  0.0006754494059985568f,
 -0.00011747678400228192f
};

constexpr int L0 = 16384;
constexpr int T1 = 8199, T2 = 4107, T3 = 2061;   // T4 = 1038
constexpr int NT = 512;

// LDS slots (float offsets; every base & size a multiple of 32 so the
// swizzle's 32-float blocks never straddle slot boundaries).
constexpr int O_A1 = 0;      // 8224: a1, then d1 (spilled from regs)
constexpr int O_A2 = 8224;   // 4128: a2, then r2
constexpr int O_A3 = 12352;  // 2080: a3, then r3
constexpr int O_D3 = 14432;  // 2080: d3, then d2 spill part B
constexpr int O_A4 = 16512;  // 1056: a4 \ then d2 spill part A (contiguous 2112)
constexpr int O_D4 = 17568;  // 1056: d4 /
constexpr int LDSF = 18624;  // 74,496 B (+hist 2KB) -> 2 blocks/CU
constexpr int O_SPA = O_A4;  // d2 quads [0,528)
constexpr int O_SPB = O_D3;  // d2 quads [528,1027)
constexpr int SPLITQ = 528;

// Permutes 4-float chunks within each 32-float block (bank decorrelation for
// the 32B-stride dwt window reads). Applied to slot-LOCAL indices.
__device__ __forceinline__ int swz(int i) { return i ^ (((i >> 5) & 3) << 2); }

// Forward DWT quad: outputs (ca,cd)[4v..4v+3] from src[8v-16 .. 8v+7].
template<bool SSWZ>
__device__ __forceinline__ void dwt_quad(const float* __restrict__ src, int Lin,
                                         int v, float4& aq, float4& dq) {
  float w[24];
  const int base = 8 * v - 16;
  if (v >= 2 && 8 * v + 7 < Lin) {
#pragma unroll
    for (int q = 0; q < 6; ++q) {
      const int idx = SSWZ ? swz(base + 4 * q) : (base + 4 * q);
      const float4 t4 = *reinterpret_cast<const float4*>(src + idx);
      w[4*q+0] = t4.x; w[4*q+1] = t4.y; w[4*q+2] = t4.z; w[4*q+3] = t4.w;
    }
  } else {
#pragma unroll
    for (int k = 0; k < 24; ++k) {
      int g = base + k;
      if (g < 0) g = -1 - g;
      else if (g >= Lin) g = 2 * Lin - 1 - g;
      w[k] = src[SSWZ ? swz(g) : g];
    }
  }
  float a[4] = {0.f,0.f,0.f,0.f};
  float d[4] = {0.f,0.f,0.f,0.f};
#pragma unroll
  for (int k = 0; k < 16; ++k) {
    const float hk = HF[k];
    const float gk = (k & 1) ? -HF[15 - k] : HF[15 - k];
#pragma unroll
    for (int p = 0; p < 4; ++p) {
      a[p] = fmaf(w[2*p + 2 + k], hk, a[p]);
      d[p] = fmaf(w[2*p + 2 + k], gk, d[p]);
    }
  }
  aq = make_float4(a[0], a[1], a[2], a[3]);
  dq = make_float4(d[0], d[1], d[2], d[3]);
}

// One inverse-DWT step (LDS->LDS) with soft-threshold: 8 outputs at 8u..8u+7.
__device__ __forceinline__ void idwt_one(const float* __restrict__ Sb, int oA,
                                         int oD, float th,
                                         float* __restrict__ Sw, int oOut, int u) {
  float A[12], Ds[12];
#pragma unroll
  for (int c = 0; c < 3; ++c) {
    const float4 a = *reinterpret_cast<const float4*>(Sb + oA + swz(4*(u+c)));
    A[4*c+0]=a.x; A[4*c+1]=a.y; A[4*c+2]=a.z; A[4*c+3]=a.w;
    const float4 d = *reinterpret_cast<const float4*>(Sb + oD + swz(4*(u+c)));
    Ds[4*c+0]=d.x; Ds[4*c+1]=d.y; Ds[4*c+2]=d.z; Ds[4*c+3]=d.w;
  }
#pragma unroll
  for (int j = 0; j < 12; ++j) {
    const float dd = Ds[j];
    const float mag = fabsf(dd) - th;
    Ds[j] = (mag > 0.f) ? copysignf(mag, dd) : 0.f;
  }
  float o[8];
#pragma unroll
  for (int e = 0; e < 8; ++e) {
    const int b = e >> 1;
    float acc = 0.f;
#pragma unroll
    for (int j = 0; j < 8; ++j) {
      const float cA = (e & 1) ? HF[15 - 2*j] : HF[14 - 2*j];
      const float cD = (e & 1) ? -HF[2*j]     : HF[2*j + 1];
      acc = fmaf(A[b + j], cA, acc);
      acc = fmaf(Ds[b + j], cD, acc);
    }
    o[e] = acc;
  }
  *reinterpret_cast<float4*>(Sw + oOut + swz(8*u))     = make_float4(o[0],o[1],o[2],o[3]);
  *reinterpret_cast<float4*>(Sw + oOut + swz(8*u + 4)) = make_float4(o[4],o[5],o[6],o[7]);
}

// Fused rec1 + final idwt: 8 outputs out[8u..8u+7]; rec1 window recomputed
// from r2/d2 (bit-identical FMA order to a materialized rec1).
__device__ __forceinline__ void final_iter(const float* __restrict__ S, float th,
                                           int u, float* __restrict__ outr) {
  const int q0 = u >> 1;
  const int dlt = 2 * (u & 1);
  float R2[16], D2[16];
#pragma unroll
  for (int c = 0; c < 4; ++c) {
    const int q = q0 + c;
    const float4 r = *reinterpret_cast<const float4*>(S + O_A2 + swz(4*q));
    R2[4*c+0]=r.x; R2[4*c+1]=r.y; R2[4*c+2]=r.z; R2[4*c+3]=r.w;
    const float4 d = (q < SPLITQ)
      ? *reinterpret_cast<const float4*>(S + O_SPA + swz(4*q))
      : *reinterpret_cast<const float4*>(S + O_SPB + swz(4*(q - SPLITQ)));
    D2[4*c+0]=d.x; D2[4*c+1]=d.y; D2[4*c+2]=d.z; D2[4*c+3]=d.w;
  }
#pragma unroll
  for (int j = 0; j < 16; ++j) {
    const float dd = D2[j];
    const float mag = fabsf(dd) - th;
    D2[j] = (mag > 0.f) ? copysignf(mag, dd) : 0.f;
  }
  float R1[12];
#pragma unroll
  for (int i = 0; i < 12; ++i) {
    const int b = dlt + (i >> 1);
    float acc = 0.f;
#pragma unroll
    for (int j = 0; j < 8; ++j) {
      const float cA = (i & 1) ? HF[15 - 2*j] : HF[14 - 2*j];
      const float cD = (i & 1) ? -HF[2*j]     : HF[2*j + 1];
      acc = fmaf(R2[b + j], cA, acc);
      acc = fmaf(D2[b + j], cD, acc);
    }
    R1[i] = acc;
  }
  float D1[12];
#pragma unroll
  for (int c = 0; c < 3; ++c) {
    const float4 d = *reinterpret_cast<const float4*>(S + O_A1 + swz(4*(u + c)));
    D1[4*c+0]=d.x; D1[4*c+1]=d.y; D1[4*c+2]=d.z; D1[4*c+3]=d.w;
  }
#pragma unroll
  for (int j = 0; j < 12; ++j) {
    const float dd = D1[j];
    const float mag = fabsf(dd) - th;
    D1[j] = (mag > 0.f) ? copysignf(mag, dd) : 0.f;
  }
  float o[8];
#pragma unroll
  for (int e = 0; e < 8; ++e) {
    const int b = e >> 1;
    float acc = 0.f;
#pragma unroll
    for (int j = 0; j < 8; ++j) {
      const float cA = (e & 1) ? HF[15 - 2*j] : HF[14 - 2*j];
      const float cD = (e & 1) ? -HF[2*j]     : HF[2*j + 1];
      acc = fmaf(R1[b + j], cA, acc);
      acc = fmaf(D1[b + j], cD, acc);
    }
    o[e] = acc;
  }
  float4* ov = reinterpret_cast<float4*>(outr + 8*u);
  ov[0] = make_float4(o[0], o[1], o[2], o[3]);
  ov[1] = make_float4(o[4], o[5], o[6], o[7]);
}

// Wave-aggregated LDS histogram increment: one atomic per distinct bin per wave.
__device__ __forceinline__ void agg_inc(unsigned* __restrict__ h, unsigned bin,
                                        bool valid) {
  unsigned long long act = __ballot(valid);
  const int lane = (int)(threadIdx.x & 63u);
  while (act) {
    const int leader = __ffsll(act) - 1;
    const unsigned lb = (unsigned)__shfl((int)bin, leader, 64);
    const unsigned long long eq = __ballot(valid && (bin == lb));
    if (lane == leader) atomicAdd(&h[lb], (unsigned)__popcll(eq));
    act &= ~eq;
  }
}

// One radix pass over the register-resident d1 values (16 main + 4 tail).
__device__ __forceinline__ void hist_pass(unsigned* __restrict__ h, int shift,
                                          unsigned pref, int tid,
                                          const float4& q0, const float4& q1,
                                          const float4& q2, const float4& q3,
                                          const float4& qx) {
  const float vals[16] = {q0.x,q0.y,q0.z,q0.w, q1.x,q1.y,q1.z,q1.w,
                          q2.x,q2.y,q2.z,q2.w, q3.x,q3.y,q3.z,q3.w};
#pragma unroll
  for (int i = 0; i < 16; ++i) {
    const unsigned v = __float_as_uint(fabsf(vals[i]));
    const bool ok = ((unsigned)(((unsigned long long)v) >> (shift + 8)) == pref);
    agg_inc(h, (v >> shift) & 255u, ok);
  }
  const float ex[4] = {qx.x, qx.y, qx.z, qx.w};
  const int qg = 2048 + tid;
#pragma unroll
  for (int e = 0; e < 4; ++e) {
    const unsigned v = __float_as_uint(fabsf(ex[e]));
    const bool ok = (tid < 8) && (4*qg + e < T1) &&
                    ((unsigned)(((unsigned long long)v) >> (shift + 8)) == pref);
    agg_inc(h, (v >> shift) & 255u, ok);
  }
}

// Wave-0 fused scan+select: 256-bin inclusive scan via shfl, then the lane
// owning the k-th count updates (sP, sK). Reads happen before any write
// (single wave, lock-step) so no extra barrier is needed.
__device__ __forceinline__ void scan_select(const unsigned* __restrict__ h,
                                            unsigned* sPp, unsigned* sKp,
                                            int lane) {
  const unsigned pref = *sPp;
  const unsigned kk   = *sKp;
  const uint4 b = *reinterpret_cast<const uint4*>(h + 4 * lane);
  const unsigned tot = b.x + b.y + b.z + b.w;
  unsigned s = tot;
#pragma unroll
  for (int off = 1; off < 64; off <<= 1) {
    const unsigned tv = __shfl_up(s, off, 64);
    if (lane >= off) s += tv;
  }
  unsigned e = s - tot;
  if (kk >= e && kk < e + b.x) { *sPp = (pref << 8) | (unsigned)(4*lane+0); *sKp = kk - e; }
  e += b.x;
  if (kk >= e && kk < e + b.y) { *sPp = (pref << 8) | (unsigned)(4*lane+1); *sKp = kk - e; }
  e += b.y;
  if (kk >= e && kk < e + b.z) { *sPp = (pref << 8) | (unsigned)(4*lane+2); *sKp = kk - e; }
  e += b.z;
  if (kk >= e && kk < e + b.w) { *sPp = (pref << 8) | (unsigned)(4*lane+3); *sKp = kk - e; }
}

__global__ __launch_bounds__(NT, 4) void fused_k(const float* __restrict__ x,
                                                 float* __restrict__ out,
                                                 float scale) {
  __shared__ float S[LDSF];
  __shared__ unsigned hist[2][256];
  __shared__ unsigned sP, sK;

  const int tid = threadIdx.x;
  const int row = blockIdx.x;
  const float* xr = x + (size_t)row * L0;

  // ---- P1: dwt1 (a1 -> A1 slot, d1 -> registers) ----
  float4 d1q0, d1q1, d1q2, d1q3, d1qx;
  {
    float4 aq;
    dwt_quad<false>(xr, L0, tid,        aq, d1q0);
    *reinterpret_cast<float4*>(S + O_A1 + swz(4*tid)) = aq;
    dwt_quad<false>(xr, L0, tid + 512,  aq, d1q1);
    *reinterpret_cast<float4*>(S + O_A1 + swz(4*(tid+512))) = aq;
    dwt_quad<false>(xr, L0, tid + 1024, aq, d1q2);
    *reinterpret_cast<float4*>(S + O_A1 + swz(4*(tid+1024))) = aq;
    dwt_quad<false>(xr, L0, tid + 1536, aq, d1q3);
    *reinterpret_cast<float4*>(S + O_A1 + swz(4*(tid+1536))) = aq;
    d1qx = make_float4(0.f, 0.f, 0.f, 0.f);
    if (tid < 8) {
      dwt_quad<false>(xr, L0, tid + 2048, aq, d1qx);
      *reinterpret_cast<float4*>(S + O_A1 + swz(4*(tid+2048))) = aq;
    }
  }
  if (tid < 256) hist[0][tid] = 0u;
  if (tid == 0) { sP = 0u; sK = 4099u; }   // rank (T1-1)/2 of T1=8199
  __syncthreads();

  // ---- P2: dwt2 (a2 -> A2, d2 -> regs) + median hist pass 1 ----
  float4 d2q0, d2q1, d2qx;
  {
    float4 aq;
    dwt_quad<true>(S + O_A1, T1, tid,       aq, d2q0);
    *reinterpret_cast<float4*>(S + O_A2 + swz(4*tid)) = aq;
    dwt_quad<true>(S + O_A1, T1, tid + 512, aq, d2q1);
    *reinterpret_cast<float4*>(S + O_A2 + swz(4*(tid+512))) = aq;
    d2qx = make_float4(0.f, 0.f, 0.f, 0.f);
    if (tid < 8) {
      dwt_quad<true>(S + O_A1, T1, tid + 1024, aq, d2qx);
      *reinterpret_cast<float4*>(S + O_A2 + swz(4*(tid+1024))) = aq;
    }
  }
  hist_pass(hist[0], 24, 0u, tid, d1q0, d1q1, d1q2, d1q3, d1qx);
  __syncthreads();

  // ---- P3: dwt3 + spill reg-d1 into A1 (a1 dead) + scan/select 1 ----
  {
    float4 aq, dq;
    dwt_quad<true>(S + O_A2, T2, tid, aq, dq);
    *reinterpret_cast<float4*>(S + O_A3 + swz(4*tid)) = aq;
    *reinterpret_cast<float4*>(S + O_D3 + swz(4*tid)) = dq;
    if (tid < 8) {
      dwt_quad<true>(S + O_A2, T2, tid + 512, aq, dq);
      *reinterpret_cast<float4*>(S + O_A3 + swz(4*(tid+512))) = aq;
      *reinterpret_cast<float4*>(S + O_D3 + swz(4*(tid+512))) = dq;
    }
  }
  *reinterpret_cast<float4*>(S + O_A1 + swz(4*tid))        = d1q0;
  *reinterpret_cast<float4*>(S + O_A1 + swz(4*(tid+512)))  = d1q1;
  *reinterpret_cast<float4*>(S + O_A1 + swz(4*(tid+1024))) = d1q2;
  *reinterpret_cast<float4*>(S + O_A1 + swz(4*(tid+1536))) = d1q3;
  if (tid < 2)
    *reinterpret_cast<float4*>(S + O_A1 + swz(4*(tid+2048))) = d1qx;
  if (tid < 64) scan_select(hist[0], &sP, &sK, tid);
  else if (tid >= 256) hist[1][tid - 256] = 0u;
  __syncthreads();

  // ---- P4: dwt4 + hist pass 2 ----
  if (tid < 264) {
    float4 aq, dq;
    dwt_quad<true>(S + O_A3, T3, tid, aq, dq);
    *reinterpret_cast<float4*>(S + O_A4 + swz(4*tid)) = aq;
    *reinterpret_cast<float4*>(S + O_D4 + swz(4*tid)) = dq;
  }
  hist_pass(hist[1], 16, sP, tid, d1q0, d1q1, d1q2, d1q3, d1qx);
  __syncthreads();

  // ---- P5..P9: remaining radix passes ----
  if (tid < 64) scan_select(hist[1], &sP, &sK, tid);
  else if (tid >= 256) hist[0][tid - 256] = 0u;
  __syncthreads();
  hist_pass(hist[0], 8, sP, tid, d1q0, d1q1, d1q2, d1q3, d1qx);
  __syncthreads();
  if (tid < 64) scan_select(hist[0], &sP, &sK, tid);
  else if (tid >= 256) hist[1][tid - 256] = 0u;
  __syncthreads();
  hist_pass(hist[1], 0, sP, tid, d1q0, d1q1, d1q2, d1q3, d1qx);
  __syncthreads();
  if (tid < 64) scan_select(hist[1], &sP, &sK, tid);
  __syncthreads();

  const float th = __uint_as_float(sP) * scale;

  // ---- P10: rec3 = idwt(a4, d4) -> A3 (a3 dead) ----
  if (tid < 260) idwt_one(S, O_A4, O_D4, th, S, O_A3, tid);
  __syncthreads();

  // ---- P11: rec2 = idwt(r3, d3) -> A2 (a2 dead) + d2 spill part A ----
  idwt_one(S, O_A3, O_D3, th, S, O_A2, tid);
  if (tid < 4) idwt_one(S, O_A3, O_D3, th, S, O_A2, 512 + tid);
  *reinterpret_cast<float4*>(S + O_SPA + swz(4*tid)) = d2q0;     // quads 0..511
  if (tid < 16)
    *reinterpret_cast<float4*>(S + O_SPA + swz(4*(tid+512))) = d2q1;  // 512..527
  __syncthreads();

  // ---- P12: d2 spill part B into D3 (d3 dead after rec2) ----
  if (tid >= 16)
    *reinterpret_cast<float4*>(S + O_SPB + swz(4*(tid + 512 - SPLITQ))) = d2q1;
  if (tid < 3)
    *reinterpret_cast<float4*>(S + O_SPB + swz(4*(tid + 1024 - SPLITQ))) = d2qx;
  __syncthreads();

  // ---- P13: fused rec1 + final idwt -> global ----
  float* outr = out + (size_t)row * L0;
#pragma unroll
  for (int m = 0; m < 4; ++m)
    final_iter(S, th, tid + 512*m, outr);
}

extern "C" void kernel_launch(void* const* d_in, const int* in_sizes, int n_in,
                              void* d_out, int out_size, void* d_ws, size_t ws_size,
                              hipStream_t stream) {
  (void)n_in; (void)out_size; (void)d_ws; (void)ws_size;
  const float* x = (const float*)d_in[0];
  float* out = (float*)d_out;
  const int rows = in_sizes[0] / L0;   // 2048
  const float scale = (float)(sqrt(2.0 * log((double)L0)) / 0.6745);
  fused_k<<<dim3((unsigned)rows), dim3(NT), 0, stream>>>(x, out, scale);
}

// Round 5
// 379.496 us; speedup vs baseline: 2.5500x; 2.5500x over previous
//
#include <hip/hip_runtime.h>
#include <math.h>

// WaveletDenoiser — R7 (= R6 resubmit + histogram-aggregation fix).
//
// R6 bench was an infra failure (container died twice); source re-audited, no
// correctness bug found. One perf defect fixed: wave-aggregated histogram
// atomics only help pass 1 (exponent-byte bins, ~6 hot bins). Passes 2-4 bin
// near-uniform mantissa bits, where plain atomicAdd is conflict-free and the
// ballot/leader loop would serialize ~64 iterations/value. AGG is now a
// template param: pass 1 aggregated, passes 2-4 plain.
//
// Structure (from R6):
//   - d1 in global workspace (written P1, read by 4 median passes + final
//     idwt; L2-resident: 2 blk/CU x 32 CU x 33KB = 2.1MB < 4MB/XCD L2).
//   - LDS: a1-slot(8224, reused a3/d3/a4/d4/r3) + a2(4128, then r2) +
//     d2(4128) + 4 hist = 70KB -> 2 blocks/CU at any VGPR <= 128.
//     Plain __launch_bounds__(512) — NO min-waves arg (R5's 64-VGPR spill trap).
//   - Median: redundant per-wave scans, (prefix,rank) in registers, 4 hist
//     buffers cleared once, 9 barriers total, scan/dwt/hist mixed per phase.
// Per-output FMA order unchanged -> bit-identical to R4.

constexpr float HF[16] = {
  0.05441584224308161f,     0.3128715909144659f,     0.6756307362980128f,
  0.5853546836548691f,     -0.015829105256023893f,  -0.2840155429624281f,
  0.00047248457399797254f,  0.128747426620186f,     -0.01736930100202211f,
 -0.04408825393106472f,     0.013981027917015516f,   0.008746094047015655f,
 -0.00487035299301066f,    -0.0003917403729959771f,  0.0006754494059985568f,
 -0.00011747678400228192f
};

constexpr int L0 = 16384;
constexpr int T1 = 8199, T2 = 4107, T3 = 2061;   // T4 = 1038
constexpr int NT = 512;
constexpr int D1S = 8224;                        // global d1 row stride (floats)

// LDS float offsets (all sub-bases multiples of 32 for swizzle-block alignment)
constexpr int O_A1 = 0;      // 8224: a1 (P1->P2); then a3/d3/a4/d4; r3 over a3
constexpr int O_A3 = 0;      // 2080 (2064 used); r3 later
constexpr int O_D3 = 2080;   // 2080 (2064 used)
constexpr int O_A4 = 4160;   // 1056 (1040 used)
constexpr int O_D4 = 5216;   // 1056 (1040 used)
constexpr int O_A2 = 8224;   // 4128 (4112 used): a2, then r2
constexpr int O_D2 = 12352;  // 4128 (4112 used): d2
constexpr int LDSF = 16480;  // 65,920 B (+4KB hist) -> 2 blocks/CU

// Permutes 4-float chunks within each 32-float (128B) block; preserves float4
// alignment (bits [1:0] untouched). Decorrelates the 32B-stride window reads.
__device__ __forceinline__ int swz(int i) { return i ^ (((i >> 5) & 3) << 2); }

// Forward DWT quad: outputs (ca,cd)[4v..4v+3] from src[8v-16 .. 8v+7].
template<bool SSWZ>
__device__ __forceinline__ void dwt_quad(const float* __restrict__ src, int Lin,
                                         int v, float4& aq, float4& dq) {
  float w[24];
  const int base = 8 * v - 16;
  if (v >= 2 && 8 * v + 7 < Lin) {
#pragma unroll
    for (int q = 0; q < 6; ++q) {
      const int idx = SSWZ ? swz(base + 4 * q) : (base + 4 * q);
      const float4 t4 = *reinterpret_cast<const float4*>(src + idx);
      w[4*q+0] = t4.x; w[4*q+1] = t4.y; w[4*q+2] = t4.z; w[4*q+3] = t4.w;
    }
  } else {
#pragma unroll
    for (int k = 0; k < 24; ++k) {
      int g = base + k;
      if (g < 0) g = -1 - g;
      else if (g >= Lin) g = 2 * Lin - 1 - g;
      w[k] = src[SSWZ ? swz(g) : g];
    }
  }
  float a[4] = {0.f,0.f,0.f,0.f};
  float d[4] = {0.f,0.f,0.f,0.f};
#pragma unroll
  for (int k = 0; k < 16; ++k) {
    const float hk = HF[k];
    const float gk = (k & 1) ? -HF[15 - k] : HF[15 - k];
#pragma unroll
    for (int p = 0; p < 4; ++p) {
      a[p] = fmaf(w[2*p + 2 + k], hk, a[p]);
      d[p] = fmaf(w[2*p + 2 + k], gk, d[p]);
    }
  }
  aq = make_float4(a[0], a[1], a[2], a[3]);
  dq = make_float4(d[0], d[1], d[2], d[3]);
}

// One inverse-DWT step (LDS->LDS) with soft-threshold: 8 outputs at 8u..8u+7.
__device__ __forceinline__ void idwt_one(const float* __restrict__ Sb, int oA,
                                         int oD, float th,
                                         float* __restrict__ Sw, int oOut, int u) {
  float A[12], Ds[12];
#pragma unroll
  for (int c = 0; c < 3; ++c) {
    const float4 a = *reinterpret_cast<const float4*>(Sb + oA + swz(4*(u+c)));
    A[4*c+0]=a.x; A[4*c+1]=a.y; A[4*c+2]=a.z; A[4*c+3]=a.w;
    const float4 d = *reinterpret_cast<const float4*>(Sb + oD + swz(4*(u+c)));
    Ds[4*c+0]=d.x; Ds[4*c+1]=d.y; Ds[4*c+2]=d.z; Ds[4*c+3]=d.w;
  }
#pragma unroll
  for (int j = 0; j < 12; ++j) {
    const float dd = Ds[j];
    const float mag = fabsf(dd) - th;
    Ds[j] = (mag > 0.f) ? copysignf(mag, dd) : 0.f;
  }
  float o[8];
#pragma unroll
  for (int e = 0; e < 8; ++e) {
    const int b = e >> 1;
    float acc = 0.f;
#pragma unroll
    for (int j = 0; j < 8; ++j) {
      const float cA = (e & 1) ? HF[15 - 2*j] : HF[14 - 2*j];
      const float cD = (e & 1) ? -HF[2*j]     : HF[2*j + 1];
      acc = fmaf(A[b + j], cA, acc);
      acc = fmaf(Ds[b + j], cD, acc);
    }
    o[e] = acc;
  }
  *reinterpret_cast<float4*>(Sw + oOut + swz(8*u))     = make_float4(o[0],o[1],o[2],o[3]);
  *reinterpret_cast<float4*>(Sw + oOut + swz(8*u + 4)) = make_float4(o[4],o[5],o[6],o[7]);
}

// Fused rec1 + final idwt: 8 outputs out[8u..8u+7]; rec1 window recomputed
// from r2 (LDS) + d2 (LDS); d1 read from global. Bit-identical FMA order.
__device__ __forceinline__ void final_iter(const float* __restrict__ S,
                                           const float* __restrict__ d1r,
                                           float th, int u,
                                           float* __restrict__ outr) {
  const int q0 = u >> 1;
  const int dlt = 2 * (u & 1);
  float R2[16], D2[16];
#pragma unroll
  for (int c = 0; c < 4; ++c) {
    const float4 r = *reinterpret_cast<const float4*>(S + O_A2 + swz(4*(q0+c)));
    R2[4*c+0]=r.x; R2[4*c+1]=r.y; R2[4*c+2]=r.z; R2[4*c+3]=r.w;
    const float4 d = *reinterpret_cast<const float4*>(S + O_D2 + swz(4*(q0+c)));
    D2[4*c+0]=d.x; D2[4*c+1]=d.y; D2[4*c+2]=d.z; D2[4*c+3]=d.w;
  }
#pragma unroll
  for (int j = 0; j < 16; ++j) {
    const float dd = D2[j];
    const float mag = fabsf(dd) - th;
    D2[j] = (mag > 0.f) ? copysignf(mag, dd) : 0.f;
  }
  float R1[12];
#pragma unroll
  for (int i = 0; i < 12; ++i) {
    const int b = dlt + (i >> 1);
    float acc = 0.f;
#pragma unroll
    for (int j = 0; j < 8; ++j) {
      const float cA = (i & 1) ? HF[15 - 2*j] : HF[14 - 2*j];
      const float cD = (i & 1) ? -HF[2*j]     : HF[2*j + 1];
      acc = fmaf(R2[b + j], cA, acc);
      acc = fmaf(D2[b + j], cD, acc);
    }
    R1[i] = acc;
  }
  float D1[12];
#pragma unroll
  for (int c = 0; c < 3; ++c) {
    const float4 d = *reinterpret_cast<const float4*>(d1r + 4*(u + c));
    D1[4*c+0]=d.x; D1[4*c+1]=d.y; D1[4*c+2]=d.z; D1[4*c+3]=d.w;
  }
#pragma unroll
  for (int j = 0; j < 12; ++j) {
    const float dd = D1[j];
    const float mag = fabsf(dd) - th;
    D1[j] = (mag > 0.f) ? copysignf(mag, dd) : 0.f;
  }
  float o[8];
#pragma unroll
  for (int e = 0; e < 8; ++e) {
    const int b = e >> 1;
    float acc = 0.f;
#pragma unroll
    for (int j = 0; j < 8; ++j) {
      const float cA = (e & 1) ? HF[15 - 2*j] : HF[14 - 2*j];
      const float cD = (e & 1) ? -HF[2*j]     : HF[2*j + 1];
      acc = fmaf(R1[b + j], cA, acc);
      acc = fmaf(D1[b + j], cD, acc);
    }
    o[e] = acc;
  }
  float4* ov = reinterpret_cast<float4*>(outr + 8*u);
  ov[0] = make_float4(o[0], o[1], o[2], o[3]);
  ov[1] = make_float4(o[4], o[5], o[6], o[7]);
}

// Wave-aggregated LDS histogram increment: one atomic per distinct bin per wave.
__device__ __forceinline__ void agg_inc(unsigned* __restrict__ h, unsigned bin,
                                        bool valid) {
  unsigned long long act = __ballot(valid);
  const int lane = (int)(threadIdx.x & 63u);
  while (act) {
    const int leader = __ffsll(act) - 1;
    const unsigned lb = (unsigned)__shfl((int)bin, leader, 64);
    const unsigned long long eq = __ballot(valid && (bin == lb));
    if (lane == leader) atomicAdd(&h[lb], (unsigned)__popcll(eq));
    act &= ~eq;
  }
}

// One radix pass over global d1 (quads 0..2049 cover indices 0..8198 < T1).
// AGG: wave-aggregated atomics (pass 1 only — exponent bins are concentrated;
// later passes bin uniform mantissa bits where plain atomics don't conflict).
template<int SH, bool AGG>
__device__ __forceinline__ void hist_pass_g(const float* __restrict__ d1r,
                                            unsigned* __restrict__ h,
                                            unsigned pref, int tid) {
#pragma unroll
  for (int m = 0; m < 5; ++m) {
    const int q = tid + NT * m;
    if (q < 2050) {
      const float4 dv = *reinterpret_cast<const float4*>(d1r + 4*q);
      const float c4[4] = {dv.x, dv.y, dv.z, dv.w};
#pragma unroll
      for (int e = 0; e < 4; ++e) {
        const unsigned v = __float_as_uint(fabsf(c4[e]));
        bool ok = (4*q + e) < T1;
        if constexpr (SH < 24) ok = ok && ((v >> (SH + 8)) == pref);
        if constexpr (AGG) {
          agg_inc(h, (v >> SH) & 255u, ok);
        } else {
          if (ok) atomicAdd(&h[(v >> SH) & 255u], 1u);
        }
      }
    }
  }
}

// Per-wave redundant 256-bin scan + rank-select; updates (pref,kk) in regs and
// broadcasts to all 64 lanes. No LDS writes, no extra barriers.
__device__ __forceinline__ void wave_scan(const unsigned* __restrict__ h,
                                          unsigned& pref, unsigned& kk) {
  const int lane = (int)(threadIdx.x & 63u);
  const uint4 b = *reinterpret_cast<const uint4*>(h + 4 * lane);
  const unsigned tot = b.x + b.y + b.z + b.w;
  unsigned s = tot;
#pragma unroll
  for (int off = 1; off < 64; off <<= 1) {
    const unsigned tv = __shfl_up(s, off, 64);
    if (lane >= off) s += tv;
  }
  unsigned e = s - tot;
  unsigned np = 0u, nk = 0u;
  bool found = false;
  const unsigned cnt[4] = {b.x, b.y, b.z, b.w};
#pragma unroll
  for (int j = 0; j < 4; ++j) {
    if (!found && kk >= e && kk < e + cnt[j]) {
      np = (pref << 8) | (unsigned)(4*lane + j);
      nk = kk - e;
      found = true;
    }
    e += cnt[j];
  }
  const unsigned long long m = __ballot(found);
  const int src = __ffsll((long long)m) - 1;
  pref = (unsigned)__shfl((int)np, src, 64);
  kk   = (unsigned)__shfl((int)nk, src, 64);
}

__global__ __launch_bounds__(NT) void fused_k(const float* __restrict__ x,
                                              float* __restrict__ out,
                                              float* __restrict__ d1g,
                                              float scale) {
  __shared__ float S[LDSF];
  __shared__ unsigned hist[4][256];

  const int tid = threadIdx.x;
  const int row = blockIdx.x;
  const float* xr = x + (size_t)row * L0;
  float* d1r = d1g + (size_t)row * D1S;
  unsigned pref = 0u, kk = 4099u;          // rank (T1-1)/2 of T1=8199

  if (tid < 256) {
    hist[0][tid] = 0u; hist[1][tid] = 0u; hist[2][tid] = 0u; hist[3][tid] = 0u;
  }
  __syncthreads();                                            // B0

  // P1: dwt1 (2056 quads): a1 -> LDS, d1 -> global (linear float4)
#pragma unroll
  for (int m = 0; m < 5; ++m) {
    const int v = tid + NT * m;
    if (v < 2056) {
      float4 aq, dq;
      dwt_quad<false>(xr, L0, v, aq, dq);
      *reinterpret_cast<float4*>(S + O_A1 + swz(4*v)) = aq;
      *reinterpret_cast<float4*>(d1r + 4*v) = dq;
    }
  }
  __syncthreads();                                            // B1

  // P2: dwt2 (1028 quads) + hist pass 1 (aggregated — exponent bins)
#pragma unroll
  for (int m = 0; m < 3; ++m) {
    const int v = tid + NT * m;
    if (v < 1028) {
      float4 aq, dq;
      dwt_quad<true>(S + O_A1, T1, v, aq, dq);
      *reinterpret_cast<float4*>(S + O_A2 + swz(4*v)) = aq;
      *reinterpret_cast<float4*>(S + O_D2 + swz(4*v)) = dq;
    }
  }
  hist_pass_g<24, true>(d1r, hist[0], 0u, tid);
  __syncthreads();                                            // B2

  // P3: scan1 ; dwt3 (516 quads) ; hist pass 2 (plain atomics)
  wave_scan(hist[0], pref, kk);
#pragma unroll
  for (int m = 0; m < 2; ++m) {
    const int v = tid + NT * m;
    if (v < 516) {
      float4 aq, dq;
      dwt_quad<true>(S + O_A2, T2, v, aq, dq);
      *reinterpret_cast<float4*>(S + O_A3 + swz(4*v)) = aq;
      *reinterpret_cast<float4*>(S + O_D3 + swz(4*v)) = dq;
    }
  }
  hist_pass_g<16, false>(d1r, hist[1], pref, tid);
  __syncthreads();                                            // B3

  // P4: scan2 ; dwt4 (260 quads) ; hist pass 3
  wave_scan(hist[1], pref, kk);
  if (tid < 260) {
    float4 aq, dq;
    dwt_quad<true>(S + O_A3, T3, tid, aq, dq);
    *reinterpret_cast<float4*>(S + O_A4 + swz(4*tid)) = aq;
    *reinterpret_cast<float4*>(S + O_D4 + swz(4*tid)) = dq;
  }
  hist_pass_g<8, false>(d1r, hist[2], pref, tid);
  __syncthreads();                                            // B4

  // P5: scan3 ; hist pass 4
  wave_scan(hist[2], pref, kk);
  hist_pass_g<0, false>(d1r, hist[3], pref, tid);
  __syncthreads();                                            // B5

  // P6: scan4 -> th ; rec3 = idwt(a4,d4) -> r3 (over a3)
  wave_scan(hist[3], pref, kk);
  const float th = __uint_as_float(pref) * scale;
  if (tid < 258) idwt_one(S, O_A4, O_D4, th, S, O_A3, tid);
  __syncthreads();                                            // B6

  // P7: rec2 = idwt(r3,d3) -> r2 (over a2), 514 windows
  idwt_one(S, O_A3, O_D3, th, S, O_A2, tid);
  if (tid < 2) idwt_one(S, O_A3, O_D3, th, S, O_A2, NT + tid);
  __syncthreads();                                            // B7

  // P8: fused rec1 + final idwt -> out (2048 windows)
  float* outr = out + (size_t)row * L0;
#pragma unroll
  for (int m = 0; m < 4; ++m)
    final_iter(S, d1r, th, tid + NT * m, outr);
}

extern "C" void kernel_launch(void* const* d_in, const int* in_sizes, int n_in,
                              void* d_out, int out_size, void* d_ws, size_t ws_size,
                              hipStream_t stream) {
  (void)n_in; (void)out_size; (void)ws_size;
  const float* x = (const float*)d_in[0];
  float* out = (float*)d_out;
  float* d1g = (float*)d_ws;               // 2048 * 8224 * 4B = 67.4 MB
  const int rows = in_sizes[0] / L0;       // 2048
  const float scale = (float)(sqrt(2.0 * log((double)L0)) / 0.6745);
  fused_k<<<dim3((unsigned)rows), dim3(NT), 0, stream>>>(x, out, d1g, scale);
}

// Round 6
// 302.789 us; speedup vs baseline: 3.1960x; 1.2533x over previous
//
#include <hip/hip_runtime.h>
#include <math.h>

// WaveletDenoiser — R8: 2-blocks/CU pipeline, VALU diet.
//
// R7 post-mortem: VALU-issue-bound (VALUBusy 72%, 2.3x R4's VALU cycles).
// Causes: agg_inc ballot loops (~15 exponent bins/wave-group, not ~6),
// 4x global d1 re-reads, fused-rec1 recompute (+500 FMA/thread).
// R8: (a) plain LDS atomics + 8-way wave-privatized pass-1 histograms
//         (hist[8][256], collisions -> LDS pipe, zero VALU loops);
//     (b) d1 median passes read 20 VGPRs (d1 computed in P1, kept in regs
//         through P5; written to global once for the final stage);
//     (c) rec1 materialized into the a1-slot (free after P7) in P8a;
//         final idwt (P8b) reads it from LDS — saves ~500 FMA/thread.
// Same idwt tap order as R4/R7 -> same numerics. LDS 77.2KB -> 2 blocks/CU.

constexpr float HF[16] = {
  0.05441584224308161f,     0.3128715909144659f,     0.6756307362980128f,
  0.5853546836548691f,     -0.015829105256023893f,  -0.2840155429624281f,
  0.00047248457399797254f,  0.128747426620186f,     -0.01736930100202211f,
 -0.04408825393106472f,     0.013981027917015516f,   0.008746094047015655f,
 -0.00487035299301066f,    -0.0003917403729959771f,  0.0006754494059985568f,
 -0.00011747678400228192f
};

constexpr int L0 = 16384;
constexpr int T1 = 8199, T2 = 4107, T3 = 2061;   // T4 = 1038
constexpr int NT = 512;
constexpr int D1S = 8224;                        // global d1 row stride (floats)

// LDS float offsets (all sub-bases multiples of 32 for swizzle-block alignment)
constexpr int O_A1 = 0;      // 8224: a1 (P1->P2); then a3/d3/a4/d4; rec1 in P8a
constexpr int O_A3 = 0;      // 2080 (2064 used); r3 later
constexpr int O_D3 = 2080;   // 2080 (2064 used)
constexpr int O_A4 = 4160;   // 1056 (1040 used)
constexpr int O_D4 = 5216;   // 1056 (1040 used)
constexpr int O_A2 = 8224;   // 4128 (4112 used): a2, then r2
constexpr int O_D2 = 12352;  // 4128 (4112 used): d2
constexpr int LDSF = 16480;  // 65,920 B
constexpr int NHIST = 11 * 256;  // 8 pass-1 sub-hists + 3 single hists (11KB)

// Permutes 4-float chunks within each 32-float (128B) block; preserves float4
// alignment (bits [1:0] untouched). Decorrelates the 32B-stride window reads.
__device__ __forceinline__ int swz(int i) { return i ^ (((i >> 5) & 3) << 2); }

// Forward DWT quad: outputs (ca,cd)[4v..4v+3] from src[8v-16 .. 8v+7].
template<bool SSWZ>
__device__ __forceinline__ void dwt_quad(const float* __restrict__ src, int Lin,
                                         int v, float4& aq, float4& dq) {
  float w[24];
  const int base = 8 * v - 16;
  if (v >= 2 && 8 * v + 7 < Lin) {
#pragma unroll
    for (int q = 0; q < 6; ++q) {
      const int idx = SSWZ ? swz(base + 4 * q) : (base + 4 * q);
      const float4 t4 = *reinterpret_cast<const float4*>(src + idx);
      w[4*q+0] = t4.x; w[4*q+1] = t4.y; w[4*q+2] = t4.z; w[4*q+3] = t4.w;
    }
  } else {
#pragma unroll
    for (int k = 0; k < 24; ++k) {
      int g = base + k;
      if (g < 0) g = -1 - g;
      else if (g >= Lin) g = 2 * Lin - 1 - g;
      w[k] = src[SSWZ ? swz(g) : g];
    }
  }
  float a[4] = {0.f,0.f,0.f,0.f};
  float d[4] = {0.f,0.f,0.f,0.f};
#pragma unroll
  for (int k = 0; k < 16; ++k) {
    const float hk = HF[k];
    const float gk = (k & 1) ? -HF[15 - k] : HF[15 - k];
#pragma unroll
    for (int p = 0; p < 4; ++p) {
      a[p] = fmaf(w[2*p + 2 + k], hk, a[p]);
      d[p] = fmaf(w[2*p + 2 + k], gk, d[p]);
    }
  }
  aq = make_float4(a[0], a[1], a[2], a[3]);
  dq = make_float4(d[0], d[1], d[2], d[3]);
}

// One inverse-DWT step (LDS->LDS) with soft-threshold: 8 outputs at 8u..8u+7.
__device__ __forceinline__ void idwt_one(const float* __restrict__ Sb, int oA,
                                         int oD, float th,
                                         float* __restrict__ Sw, int oOut, int u) {
  float A[12], Ds[12];
#pragma unroll
  for (int c = 0; c < 3; ++c) {
    const float4 a = *reinterpret_cast<const float4*>(Sb + oA + swz(4*(u+c)));
    A[4*c+0]=a.x; A[4*c+1]=a.y; A[4*c+2]=a.z; A[4*c+3]=a.w;
    const float4 d = *reinterpret_cast<const float4*>(Sb + oD + swz(4*(u+c)));
    Ds[4*c+0]=d.x; Ds[4*c+1]=d.y; Ds[4*c+2]=d.z; Ds[4*c+3]=d.w;
  }
#pragma unroll
  for (int j = 0; j < 12; ++j) {
    const float dd = Ds[j];
    const float mag = fabsf(dd) - th;
    Ds[j] = (mag > 0.f) ? copysignf(mag, dd) : 0.f;
  }
  float o[8];
#pragma unroll
  for (int e = 0; e < 8; ++e) {
    const int b = e >> 1;
    float acc = 0.f;
#pragma unroll
    for (int j = 0; j < 8; ++j) {
      const float cA = (e & 1) ? HF[15 - 2*j] : HF[14 - 2*j];
      const float cD = (e & 1) ? -HF[2*j]     : HF[2*j + 1];
      acc = fmaf(A[b + j], cA, acc);
      acc = fmaf(Ds[b + j], cD, acc);
    }
    o[e] = acc;
  }
  *reinterpret_cast<float4*>(Sw + oOut + swz(8*u))     = make_float4(o[0],o[1],o[2],o[3]);
  *reinterpret_cast<float4*>(Sw + oOut + swz(8*u + 4)) = make_float4(o[4],o[5],o[6],o[7]);
}

// Final idwt: A = rec1 (swizzled LDS, a1 slot), D = d1 (global, thresholded),
// 8 outputs out[8u..8u+7]. Same tap/accumulation order as idwt_one.
__device__ __forceinline__ void final_one(const float* __restrict__ S,
                                          const float* __restrict__ d1r,
                                          float th, int u,
                                          float* __restrict__ outr) {
  float A[12], Ds[12];
#pragma unroll
  for (int c = 0; c < 3; ++c) {
    const float4 a = *reinterpret_cast<const float4*>(S + O_A1 + swz(4*(u+c)));
    A[4*c+0]=a.x; A[4*c+1]=a.y; A[4*c+2]=a.z; A[4*c+3]=a.w;
    const float4 d = *reinterpret_cast<const float4*>(d1r + 4*(u+c));
    Ds[4*c+0]=d.x; Ds[4*c+1]=d.y; Ds[4*c+2]=d.z; Ds[4*c+3]=d.w;
  }
#pragma unroll
  for (int j = 0; j < 12; ++j) {
    const float dd = Ds[j];
    const float mag = fabsf(dd) - th;
    Ds[j] = (mag > 0.f) ? copysignf(mag, dd) : 0.f;
  }
  float o[8];
#pragma unroll
  for (int e = 0; e < 8; ++e) {
    const int b = e >> 1;
    float acc = 0.f;
#pragma unroll
    for (int j = 0; j < 8; ++j) {
      const float cA = (e & 1) ? HF[15 - 2*j] : HF[14 - 2*j];
      const float cD = (e & 1) ? -HF[2*j]     : HF[2*j + 1];
      acc = fmaf(A[b + j], cA, acc);
      acc = fmaf(Ds[b + j], cD, acc);
    }
    o[e] = acc;
  }
  float4* ov = reinterpret_cast<float4*>(outr + 8*u);
  ov[0] = make_float4(o[0], o[1], o[2], o[3]);
  ov[1] = make_float4(o[4], o[5], o[6], o[7]);
}

// One radix pass over the register-resident d1 (5 float4/thread; quad m is at
// global quad index tid + 512*m; m=4 exists only for tid<8). Plain atomics.
template<int SH>
__device__ __forceinline__ void hist_regs(const float4* __restrict__ q,
                                          unsigned* __restrict__ h,
                                          unsigned pref, int tid) {
#pragma unroll
  for (int m = 0; m < 5; ++m) {
    const float c4[4] = {q[m].x, q[m].y, q[m].z, q[m].w};
    const int qi = tid + NT * m;
#pragma unroll
    for (int e = 0; e < 4; ++e) {
      const unsigned v = __float_as_uint(fabsf(c4[e]));
      bool ok = (m < 4) ? true : ((tid < 8) && (4*qi + e < T1));
      if constexpr (SH < 24) ok = ok && ((v >> (SH + 8)) == pref);
      if (ok) atomicAdd(&h[(v >> SH) & 255u], 1u);
    }
  }
}

// Per-wave redundant scan+select over NS sub-histograms (summed per bin);
// updates (pref,kk) in registers, broadcast to all 64 lanes.
template<int NS>
__device__ __forceinline__ void wave_scan(const unsigned* __restrict__ hbase,
                                          unsigned& pref, unsigned& kk,
                                          int lane) {
  unsigned c0 = 0, c1 = 0, c2 = 0, c3 = 0;
#pragma unroll
  for (int w = 0; w < NS; ++w) {
    const uint4 t = *reinterpret_cast<const uint4*>(hbase + 256*w + 4*lane);
    c0 += t.x; c1 += t.y; c2 += t.z; c3 += t.w;
  }
  const unsigned tot = c0 + c1 + c2 + c3;
  unsigned s = tot;
#pragma unroll
  for (int off = 1; off < 64; off <<= 1) {
    const unsigned tv = __shfl_up(s, off, 64);
    if (lane >= off) s += tv;
  }
  unsigned e = s - tot;
  unsigned np = 0u, nk = 0u;
  bool found = false;
  const unsigned cnt[4] = {c0, c1, c2, c3};
#pragma unroll
  for (int j = 0; j < 4; ++j) {
    if (!found && kk >= e && kk < e + cnt[j]) {
      np = (pref << 8) | (unsigned)(4*lane + j);
      nk = kk - e;
      found = true;
    }
    e += cnt[j];
  }
  const unsigned long long m = __ballot(found);
  const int src = __ffsll((long long)m) - 1;
  pref = (unsigned)__shfl((int)np, src, 64);
  kk   = (unsigned)__shfl((int)nk, src, 64);
}

__global__ __launch_bounds__(NT) void fused_k(const float* __restrict__ x,
                                              float* __restrict__ out,
                                              float* __restrict__ d1g,
                                              float scale) {
  __shared__ float S[LDSF];
  __shared__ unsigned hist[NHIST];   // [0,2048): pass1 [8][256]; then 3x256

  const int tid  = threadIdx.x;
  const int lane = tid & 63;
  const int wave = tid >> 6;
  const int row = blockIdx.x;
  const float* xr = x + (size_t)row * L0;
  float* d1r = d1g + (size_t)row * D1S;
  unsigned pref = 0u, kk = 4099u;          // rank (T1-1)/2 of T1=8199

  // P1: dwt1 (2056 quads): a1 -> LDS, d1 -> 5 regs + global; clear hists
  float4 d1q[5];
  {
    float4 aq;
#pragma unroll
    for (int m = 0; m < 4; ++m) {
      const int v = tid + NT * m;
      dwt_quad<false>(xr, L0, v, aq, d1q[m]);
      *reinterpret_cast<float4*>(S + O_A1 + swz(4*v)) = aq;
      *reinterpret_cast<float4*>(d1r + 4*v) = d1q[m];
    }
    d1q[4] = make_float4(0.f, 0.f, 0.f, 0.f);
    if (tid < 8) {
      const int v = tid + 2048;
      dwt_quad<false>(xr, L0, v, aq, d1q[4]);
      *reinterpret_cast<float4*>(S + O_A1 + swz(4*v)) = aq;
      *reinterpret_cast<float4*>(d1r + 4*v) = d1q[4];
    }
  }
  for (int i = tid; i < NHIST; i += NT) hist[i] = 0u;
  __syncthreads();                                            // B1

  // P2: dwt2 (1028 quads) + hist pass 1 (wave-privatized, plain atomics)
#pragma unroll
  for (int m = 0; m < 3; ++m) {
    const int v = tid + NT * m;
    if (v < 1028) {
      float4 aq, dq;
      dwt_quad<true>(S + O_A1, T1, v, aq, dq);
      *reinterpret_cast<float4*>(S + O_A2 + swz(4*v)) = aq;
      *reinterpret_cast<float4*>(S + O_D2 + swz(4*v)) = dq;
    }
  }
  hist_regs<24>(d1q, hist + 256 * wave, 0u, tid);
  __syncthreads();                                            // B2

  // P3: scan1 (8 sub-hists) ; dwt3 (516 quads) ; hist pass 2
  wave_scan<8>(hist, pref, kk, lane);
#pragma unroll
  for (int m = 0; m < 2; ++m) {
    const int v = tid + NT * m;
    if (v < 516) {
      float4 aq, dq;
      dwt_quad<true>(S + O_A2, T2, v, aq, dq);
      *reinterpret_cast<float4*>(S + O_A3 + swz(4*v)) = aq;
      *reinterpret_cast<float4*>(S + O_D3 + swz(4*v)) = dq;
    }
  }
  hist_regs<16>(d1q, hist + 2048, pref, tid);
  __syncthreads();                                            // B3

  // P4: scan2 ; dwt4 (260 quads) ; hist pass 3
  wave_scan<1>(hist + 2048, pref, kk, lane);
  if (tid < 260) {
    float4 aq, dq;
    dwt_quad<true>(S + O_A3, T3, tid, aq, dq);
    *reinterpret_cast<float4*>(S + O_A4 + swz(4*tid)) = aq;
    *reinterpret_cast<float4*>(S + O_D4 + swz(4*tid)) = dq;
  }
  hist_regs<8>(d1q, hist + 2048 + 256, pref, tid);
  __syncthreads();                                            // B4

  // P5: scan3 ; hist pass 4
  wave_scan<1>(hist + 2048 + 256, pref, kk, lane);
  hist_regs<0>(d1q, hist + 2048 + 512, pref, tid);
  __syncthreads();                                            // B5

  // P6: scan4 -> th ; rec3 = idwt(a4,d4) -> r3 (over a3)
  wave_scan<1>(hist + 2048 + 512, pref, kk, lane);
  const float th = __uint_as_float(pref) * scale;
  if (tid < 258) idwt_one(S, O_A4, O_D4, th, S, O_A3, tid);
  __syncthreads();                                            // B6

  // P7: rec2 = idwt(r3,d3) -> r2 (over a2), 514 windows
  idwt_one(S, O_A3, O_D3, th, S, O_A2, tid);
  if (tid < 2) idwt_one(S, O_A3, O_D3, th, S, O_A2, NT + tid);
  __syncthreads();                                            // B7

  // P8a: rec1 = idwt(r2,d2) -> a1 slot (free since P3), 1025 windows
  idwt_one(S, O_A2, O_D2, th, S, O_A1, tid);
  idwt_one(S, O_A2, O_D2, th, S, O_A1, tid + NT);
  if (tid < 1) idwt_one(S, O_A2, O_D2, th, S, O_A1, 1024);
  __syncthreads();                                            // B8

  // P8b: final idwt (rec1 LDS + d1 global) -> out, 2048 windows
  float* outr = out + (size_t)row * L0;
#pragma unroll
  for (int m = 0; m < 4; ++m)
    final_one(S, d1r, th, tid + NT * m, outr);
}

extern "C" void kernel_launch(void* const* d_in, const int* in_sizes, int n_in,
                              void* d_out, int out_size, void* d_ws, size_t ws_size,
                              hipStream_t stream) {
  (void)n_in; (void)out_size; (void)ws_size;
  const float* x = (const float*)d_in[0];
  float* out = (float*)d_out;
  float* d1g = (float*)d_ws;               // 2048 * 8224 * 4B = 67.4 MB
  const int rows = in_sizes[0] / L0;       // 2048
  const float scale = (float)(sqrt(2.0 * log((double)L0)) / 0.6745);
  fused_k<<<dim3((unsigned)rows), dim3(NT), 0, stream>>>(x, out, d1g, scale);
}